// Round 9
// baseline (160.416 us; speedup 1.0000x reference)
//
#include <hip/hip_runtime.h>

#define C_DIM 256
#define CK_DIM 32
#define NPIX 4096
#define BATCH 4
#define LOG2E 1.4426950408889634f

typedef __attribute__((ext_vector_type(8))) short bf16x8;     // 8 bf16 = 4 VGPRs
typedef __attribute__((ext_vector_type(4))) float f32x4;
typedef __attribute__((ext_vector_type(16))) float f32x16;
typedef __attribute__((ext_vector_type(4))) unsigned short us4;

__device__ __forceinline__ unsigned short f2bf(float f) {
    union { float f; unsigned int u; } c; c.f = f;
    unsigned int r = c.u + 0x7FFFu + ((c.u >> 16) & 1u);
    return (unsigned short)(r >> 16);
}

__device__ __forceinline__ float fast_exp2(float x) {
#if __has_builtin(__builtin_amdgcn_exp2f)
    return __builtin_amdgcn_exp2f(x);
#else
    return exp2f(x);
#endif
}

// ---------------------------------------------------------------------------
// Kernel 0: pack W into bf16 [320][256]. Key rows (o<32) pre-scaled by log2e
// so S = k.q is already in the exp2 domain (softmax is scale-consistent:
// 2^(S*log2e) == e^S, and l sums match).
// ---------------------------------------------------------------------------
__global__ __launch_bounds__(256) void wprep_kernel(
    const float* __restrict__ kW, const float* __restrict__ qW,
    const float* __restrict__ vW, unsigned short* __restrict__ wbf)
{
    int i4 = (blockIdx.x * 256 + threadIdx.x) * 4;
    int o = i4 >> 8, c = i4 & 255;
    const float* src = (o < 32) ? kW + o * 256 + c
                     : (o < 64) ? qW + (o - 32) * 256 + c
                                : vW + (o - 64) * 256 + c;
    float s = (o < 32) ? LOG2E : 1.0f;
    float4 f = *(const float4*)src;
    us4 p; p.x = f2bf(f.x * s); p.y = f2bf(f.y * s);
           p.z = f2bf(f.z * s); p.w = f2bf(f.w * s);
    *(us4*)&wbf[i4] = p;
}

// ---------------------------------------------------------------------------
// Kernel A: MFMA projections. Block = (16-pixel tile, b): 1024 blocks = 4/CU
// (was 2/CU) for more TLP against W-load L2 latency. Wave w owns 80 o-rows
// (5 acc tiles, awc/awn double-buffered W prefetch).
// ---------------------------------------------------------------------------
__global__ __launch_bounds__(256) void proj_kernel(
    const float* __restrict__ x,
    const unsigned short* __restrict__ wbf,
    const float* __restrict__ key_b, const float* __restrict__ query_b,
    const float* __restrict__ value_b,
    unsigned short* __restrict__ kT,
    unsigned short* __restrict__ qT,
    unsigned short* __restrict__ vt)
{
    const int b  = blockIdx.y;
    const int n0 = blockIdx.x * 16;
    const int t  = threadIdx.x;
    const int w    = t >> 6;
    const int lane = t & 63;
    const int mrow = lane & 15;
    const int quad = lane >> 4;

    // phase1: XT[16][264] = 4224 shorts; phase2: KQS[16][72] + VS[256][24] = 7296
    __shared__ __align__(16) unsigned short smem[7296];
    #define XT(n, c)   smem[(n) * 264 + (c)]
    #define KQS(n, o)  smem[(n) * 72 + (o)]
    #define VS(c, nn)  smem[1152 + (c) * 24 + (nn)]

    // ---- stage x^T (bf16) via 4x4 register transpose; coalesced reads
    const float* xb = x + (size_t)b * C_DIM * NPIX + n0;
    {
        const int px4 = (t & 3) * 4;      // pixel group
        const int c0  = (t >> 2) * 4;     // 4 channels
        float4 r0 = *(const float4*)(xb + (size_t)(c0 + 0) * NPIX + px4);
        float4 r1 = *(const float4*)(xb + (size_t)(c0 + 1) * NPIX + px4);
        float4 r2 = *(const float4*)(xb + (size_t)(c0 + 2) * NPIX + px4);
        float4 r3 = *(const float4*)(xb + (size_t)(c0 + 3) * NPIX + px4);
        float d0[4] = {r0.x, r0.y, r0.z, r0.w};
        float d1[4] = {r1.x, r1.y, r1.z, r1.w};
        float d2[4] = {r2.x, r2.y, r2.z, r2.w};
        float d3[4] = {r3.x, r3.y, r3.z, r3.w};
        #pragma unroll
        for (int d = 0; d < 4; ++d) {
            us4 p; p.x = f2bf(d0[d]); p.y = f2bf(d1[d]);
                   p.z = f2bf(d2[d]); p.w = f2bf(d3[d]);
            *(us4*)&XT(px4 + d, c0) = p;
        }
    }
    __syncthreads();

    // ---- K-loop: 8 steps x 5 MFMA per wave, W-frags double-buffered
    f32x4 acc[5];
    #pragma unroll
    for (int ot = 0; ot < 5; ++ot) acc[ot] = (f32x4){0.f, 0.f, 0.f, 0.f};
    const int obase = w * 80;
    const unsigned short* wp = wbf + (size_t)(obase + mrow) * 256 + quad * 8;

    bf16x8 awc[5], awn[5];
    #pragma unroll
    for (int ot = 0; ot < 5; ++ot)
        awc[ot] = *(const bf16x8*)(wp + (size_t)ot * 16 * 256);

    #pragma unroll
    for (int ck = 0; ck < 256; ck += 32) {
        bf16x8 bx = *(const bf16x8*)&XT(mrow, ck + quad * 8);
        if (ck < 224) {
            #pragma unroll
            for (int ot = 0; ot < 5; ++ot)
                awn[ot] = *(const bf16x8*)(wp + (size_t)ot * 16 * 256 + ck + 32);
        }
        #pragma unroll
        for (int ot = 0; ot < 5; ++ot)
            acc[ot] = __builtin_amdgcn_mfma_f32_16x16x32_bf16(awc[ot], bx, acc[ot], 0, 0, 0);
        #pragma unroll
        for (int ot = 0; ot < 5; ++ot) awc[ot] = awn[ot];
    }
    __syncthreads();   // XT dead; reuse smem

    // ---- bias + stage (D: row o = obase+16ot+4quad+r, col n = mrow)
    #pragma unroll
    for (int ot = 0; ot < 5; ++ot) {
        #pragma unroll
        for (int r = 0; r < 4; ++r) {
            int o = obase + 16 * ot + 4 * quad + r;
            float bias = (o < 32) ? key_b[o] * LOG2E
                       : (o < 64) ? query_b[o - 32] : value_b[o - 64];
            unsigned short val = f2bf(acc[ot][r] + bias);
            if (o < 64) KQS(mrow, o) = val;
            else        VS(o - 64, mrow) = val;
        }
    }
    __syncthreads();

    // ---- coalesced stores: k/q (16 n x 32 o each)
    {
        int n = t >> 4, o4 = (t & 15) * 4;
        if (o4 < 32)
            *(us4*)&kT[((size_t)b * NPIX + n0 + n) * CK_DIM + o4] = *(const us4*)&KQS(n, o4);
        else
            *(us4*)&qT[((size_t)b * NPIX + n0 + n) * CK_DIM + (o4 - 32)] = *(const us4*)&KQS(n, o4);
    }
    // ---- coalesced stores: v (this block IS one 16-pixel vt tile)
    {
        unsigned short* vbase = vt + ((size_t)b * (NPIX / 16) + n0 / 16) * (C_DIM * 16);
        #pragma unroll
        for (int it = 0; it < 4; ++it) {
            int flat = it * 256 + t;
            int c = flat >> 2, nn = (flat & 3) * 4;
            *(us4*)&vbase[c * 16 + nn] = *(const us4*)&VS(c, nn);
        }
    }
    #undef XT
    #undef KQS
    #undef VS
}

// ---------------------------------------------------------------------------
// Kernel B: producer/consumer fused attention. i-tile 32, grid 512 = 2
// blocks/CU (cross-block overlap fills barrier stalls). Waves 0-3 produce
// S^T -> exp2 -> Pt[pp^1]; waves 4-7 consume PV (32x32x16). Scores are in
// the exp2 domain (key pre-scaled by log2e) -> bare v_exp_f32.
// ---------------------------------------------------------------------------
__global__ __launch_bounds__(512) void attn_kernel(
    const unsigned short* __restrict__ kT,
    const unsigned short* __restrict__ qT,
    const unsigned short* __restrict__ vt,
    const float* __restrict__ x, const float* __restrict__ alpha,
    float* __restrict__ out)
{
    const int f  = blockIdx.x;                   // 0..511
    const int b  = (f & 7) >> 1;                 // XCD-pair -> batch (vt L2-local)
    const int i0 = ((f >> 3) * 2 + (f & 1)) * 32;
    const int t  = threadIdx.x;
    const int w    = t >> 6;                     // 0..7
    const int lane = t & 63;
    const int mrow = lane & 15;
    const int quad = lane >> 4;
    const int m32  = lane & 31;
    const int half = lane >> 5;

    __shared__ __align__(16) unsigned short Pt[2][32][136];  // ping-pong, 17.4KB
    __shared__ float lred[4][32];

    const unsigned short* kTb = kT + (size_t)b * NPIX * CK_DIM;
    const unsigned short* qTb = qT + (size_t)b * NPIX * CK_DIM;
    const unsigned short* vtb = vt + (size_t)b * (NPIX / 16) * (C_DIM * 16);

    int pp = 0;

    if (w < 4) {
        // ================= PRODUCER =================
        const int pw = w;
        bf16x8 kf[2];
        #pragma unroll
        for (int is = 0; is < 2; ++is)
            kf[is] = *(const bf16x8*)(kTb + (size_t)(i0 + 16 * is + mrow) * CK_DIM + quad * 8);

        float lacc[2] = {0.f, 0.f};

        // produce tile 0 into Pt[0]
        #pragma unroll
        for (int js = 0; js < 2; ++js) {
            bf16x8 aq = *(const bf16x8*)(qTb + (size_t)(32 * pw + 16 * js + mrow) * CK_DIM + quad * 8);
            #pragma unroll
            for (int is = 0; is < 2; ++is) {
                f32x4 d = __builtin_amdgcn_mfma_f32_16x16x32_bf16(
                    aq, kf[is], (f32x4){0.f, 0.f, 0.f, 0.f}, 0, 0, 0);
                float p0 = fast_exp2(d[0]), p1 = fast_exp2(d[1]);
                float p2 = fast_exp2(d[2]), p3 = fast_exp2(d[3]);
                lacc[is] += (p0 + p1) + (p2 + p3);
                us4 p; p.x = f2bf(p0); p.y = f2bf(p1); p.z = f2bf(p2); p.w = f2bf(p3);
                *(us4*)&Pt[0][16 * is + mrow][32 * pw + 16 * js + 4 * quad] = p;
            }
        }
        // prefetch aq for tile 128
        bf16x8 aqc[2];
        #pragma unroll
        for (int js = 0; js < 2; ++js)
            aqc[js] = *(const bf16x8*)(qTb + (size_t)(128 + 32 * pw + 16 * js + mrow) * CK_DIM + quad * 8);

        __syncthreads();

        for (int jt = 0; jt < NPIX; jt += 128) {
            bf16x8 aqn[2];
            int jpre = (jt + 256) & (NPIX - 1);
            #pragma unroll
            for (int js = 0; js < 2; ++js)
                aqn[js] = *(const bf16x8*)(qTb + (size_t)(jpre + 32 * pw + 16 * js + mrow) * CK_DIM + quad * 8);

            if (jt + 128 < NPIX) {
                #pragma unroll
                for (int js = 0; js < 2; ++js) {
                    #pragma unroll
                    for (int is = 0; is < 2; ++is) {
                        f32x4 d = __builtin_amdgcn_mfma_f32_16x16x32_bf16(
                            aqc[js], kf[is], (f32x4){0.f, 0.f, 0.f, 0.f}, 0, 0, 0);
                        float p0 = fast_exp2(d[0]), p1 = fast_exp2(d[1]);
                        float p2 = fast_exp2(d[2]), p3 = fast_exp2(d[3]);
                        lacc[is] += (p0 + p1) + (p2 + p3);
                        us4 p; p.x = f2bf(p0); p.y = f2bf(p1); p.z = f2bf(p2); p.w = f2bf(p3);
                        *(us4*)&Pt[pp ^ 1][16 * is + mrow][32 * pw + 16 * js + 4 * quad] = p;
                    }
                }
            }
            aqc[0] = aqn[0]; aqc[1] = aqn[1];
            __syncthreads();
            pp ^= 1;
        }

        #pragma unroll
        for (int is = 0; is < 2; ++is) {
            lacc[is] += __shfl_xor(lacc[is], 16);
            lacc[is] += __shfl_xor(lacc[is], 32);
        }
        if (lane < 16) {
            #pragma unroll
            for (int is = 0; is < 2; ++is) lred[pw][16 * is + lane] = lacc[is];
        }
        __syncthreads();
    } else {
        // ================= CONSUMER =================
        const int cw = w - 4;
        const int c0 = cw * 64;

        f32x16 acc[2];   // two 32-c subtiles x full 32-i tile
        #pragma unroll
        for (int cs = 0; cs < 2; ++cs)
            #pragma unroll
            for (int r = 0; r < 16; ++r) acc[cs][r] = 0.0f;

        bf16x8 av[8][2];
        #pragma unroll
        for (int jb = 0; jb < 8; ++jb) {
            const unsigned short* vp = vtb + (size_t)jb * (C_DIM * 16)
                                       + (size_t)(c0 + m32) * 16 + half * 8;
            av[jb][0] = *(const bf16x8*)vp;
            av[jb][1] = *(const bf16x8*)(vp + 32 * 16);
        }
        __syncthreads();

        for (int jt = 0; jt < NPIX; jt += 128) {
            #pragma unroll
            for (int jb = 0; jb < 8; ++jb) {
                bf16x8 bp = *(const bf16x8*)&Pt[pp][m32][16 * jb + half * 8];
                acc[0] = __builtin_amdgcn_mfma_f32_32x32x16_bf16(av[jb][0], bp, acc[0], 0, 0, 0);
                acc[1] = __builtin_amdgcn_mfma_f32_32x32x16_bf16(av[jb][1], bp, acc[1], 0, 0, 0);
            }
            int jpre = (jt + 128) & (NPIX - 1);
            #pragma unroll
            for (int jb = 0; jb < 8; ++jb) {
                const unsigned short* vp = vtb + (size_t)(jpre / 16 + jb) * (C_DIM * 16)
                                           + (size_t)(c0 + m32) * 16 + half * 8;
                av[jb][0] = *(const bf16x8*)vp;
                av[jb][1] = *(const bf16x8*)(vp + 32 * 16);
            }
            __syncthreads();
            pp ^= 1;
        }
        __syncthreads();   // producers' lred now visible

        const float al = alpha[0];
        float l = (lred[0][m32] + lred[1][m32]) + (lred[2][m32] + lred[3][m32]);
        float rs = al / l;

        const float* xb = x + (size_t)b * C_DIM * NPIX;
        float* ob = out + (size_t)b * C_DIM * NPIX;
        const int i = i0 + m32;
        #pragma unroll
        for (int cs = 0; cs < 2; ++cs)
            #pragma unroll
            for (int r = 0; r < 16; ++r) {
                int c = c0 + 32 * cs + (r & 3) + 8 * (r >> 2) + 4 * half;
                size_t idx = (size_t)c * NPIX + i;
                ob[idx] = acc[cs][r] * rs + xb[idx];
            }
    }
}

// ---------------------------------------------------------------------------
extern "C" void kernel_launch(void* const* d_in, const int* in_sizes, int n_in,
                              void* d_out, int out_size, void* d_ws, size_t ws_size,
                              hipStream_t stream) {
    const float* x       = (const float*)d_in[0];
    const float* key_W   = (const float*)d_in[1];
    const float* key_b   = (const float*)d_in[2];
    const float* query_W = (const float*)d_in[3];
    const float* query_b = (const float*)d_in[4];
    const float* value_W = (const float*)d_in[5];
    const float* value_b = (const float*)d_in[6];
    const float* alpha   = (const float*)d_in[7];
    float* out = (float*)d_out;

    unsigned short* kT  = (unsigned short*)d_ws;                 // [B][N][32]       1 MB
    unsigned short* qT  = kT + (size_t)BATCH * NPIX * CK_DIM;    // [B][N][32]       1 MB
    unsigned short* vt  = qT + (size_t)BATCH * NPIX * CK_DIM;    // [B][N/16][C][16] 8 MB
    unsigned short* wbf = vt + (size_t)BATCH * C_DIM * NPIX;     // [320][256]       160 KB

    wprep_kernel<<<80, 256, 0, stream>>>(key_W, query_W, value_W, wbf);

    dim3 gridA(NPIX / 16, BATCH);
    proj_kernel<<<gridA, 256, 0, stream>>>(x, wbf, key_b, query_b, value_b, kT, qT, vt);

    attn_kernel<<<512, 512, 0, stream>>>(kT, qT, vt, x, alpha, out);
}